// Round 1
// baseline (207.812 us; speedup 1.0000x reference)
//
#include <hip/hip_runtime.h>
#include <hip/hip_bf16.h>

// Problem constants
#define SEQ 4096
#define NB  4
#define DMOD 512
#define DHD 64

typedef __attribute__((ext_vector_type(8))) short short8;
typedef __attribute__((ext_vector_type(4))) float floatx4;

__device__ __forceinline__ unsigned short f2bf(float f) {
    union { float f; unsigned u; } v; v.f = f;
    unsigned r = v.u + 0x7fffu + ((v.u >> 16) & 1u);
    return (unsigned short)(r >> 16);
}

// ---------------- Kernel 0: transpose W (3 x 512x64 fp32) -> Wt bf16 [3][64][512]
__global__ __launch_bounds__(256) void wtrans_k(const float* __restrict__ Wq,
                                                const float* __restrict__ Wk,
                                                const float* __restrict__ Wv,
                                                unsigned short* __restrict__ Wt) {
    int idx = blockIdx.x * 256 + threadIdx.x;   // 98304 total
    int p   = idx >> 15;                        // / (64*512)
    int rem = idx & 32767;
    int n   = rem >> 9;                         // output col 0..63
    int k   = rem & 511;                        // input row 0..511
    const float* W = (p == 0) ? Wq : ((p == 1) ? Wk : Wv);
    Wt[idx] = f2bf(W[k * 64 + n]);
}

// ---------------- Kernel 1: QKV projection ----------------
// x (B*S x 512 fp32) @ Wt^T -> Qb,Kb bf16 row-major [B*S][64]; Vt bf16 [B][64][S]
// grid 256 blocks x 256 thr; 64-row M-tile; N=192 (q|k|v); K chunks of 32.
__global__ __launch_bounds__(256) void proj_k(const float* __restrict__ x,
                                              const unsigned short* __restrict__ Wt,
                                              const float* __restrict__ bq,
                                              const float* __restrict__ bk,
                                              const float* __restrict__ bv,
                                              unsigned short* __restrict__ Qb,
                                              unsigned short* __restrict__ Kb,
                                              unsigned short* __restrict__ Vt) {
    __shared__ __align__(16) unsigned short xs[64 * 40];    // 64 x (32+8 pad)
    __shared__ __align__(16) unsigned short wsh[192 * 40];  // 192 x (32+8 pad)

    int tid  = threadIdx.x;
    int l    = tid & 63;
    int wv   = tid >> 6;       // wave 0..3 = 16-row strip
    int m    = l & 15;
    int quad = l >> 4;
    int row0 = blockIdx.x * 64;

    floatx4 acc[12];
#pragma unroll
    for (int i = 0; i < 12; i++) acc[i] = (floatx4)(0.f);

    for (int kc = 0; kc < 16; kc++) {
        // stage x chunk 64x32 fp32 -> bf16 LDS
#pragma unroll
        for (int i = 0; i < 2; i++) {
            int idx = tid + i * 256;
            int row = idx >> 3, seg = idx & 7;
            float4 v = *(const float4*)(x + (row0 + row) * 512 + kc * 32 + seg * 4);
            uint2 pk;
            pk.x = (unsigned)f2bf(v.x) | ((unsigned)f2bf(v.y) << 16);
            pk.y = (unsigned)f2bf(v.z) | ((unsigned)f2bf(v.w) << 16);
            *(uint2*)(xs + row * 40 + seg * 4) = pk;
        }
        // stage Wt chunk 192x32 bf16
#pragma unroll
        for (int i = 0; i < 3; i++) {
            int idx = tid + i * 256;
            int row = idx >> 2, seg = idx & 3;
            *(int4*)(wsh + row * 40 + seg * 8) =
                *(const int4*)(Wt + row * 512 + kc * 32 + seg * 8);
        }
        __syncthreads();
        short8 a = *(const short8*)(xs + (wv * 16 + m) * 40 + quad * 8);
#pragma unroll
        for (int ct = 0; ct < 12; ct++) {
            short8 bfr = *(const short8*)(wsh + (ct * 16 + m) * 40 + quad * 8);
            acc[ct] = __builtin_amdgcn_mfma_f32_16x16x32_bf16(a, bfr, acc[ct], 0, 0, 0);
        }
        __syncthreads();
    }

    // epilogue: bias add, bf16 store
#pragma unroll
    for (int ct = 0; ct < 12; ct++) {
        int col = ct * 16 + m;  // 0..191
        float bias = (ct < 4) ? bq[col] : ((ct < 8) ? bk[col - 64] : bv[col - 128]);
        if (ct < 8) {
            unsigned short* dst = (ct < 4) ? Qb : Kb;
            int d = (ct & 3) * 16 + m;
#pragma unroll
            for (int r = 0; r < 4; r++) {
                int row = row0 + wv * 16 + quad * 4 + r;
                dst[row * 64 + d] = f2bf(acc[ct][r] + bias);
            }
        } else {
            int d = (ct - 8) * 16 + m;
            int row = row0 + wv * 16 + quad * 4;      // rows r=0..3 consecutive
            int bb = row >> 12, s = row & 4095;
            unsigned long long pk = 0;
#pragma unroll
            for (int r = 0; r < 4; r++)
                pk |= ((unsigned long long)f2bf(acc[ct][r] + bias)) << (16 * r);
            *(unsigned long long*)(Vt + ((bb * 64 + d) * 4096 + s)) = pk;
        }
    }
}

// ---------------- Kernel 2: flash attention ----------------
// grid 256 = B*(S/64) blocks x 512 thr (8 waves). 64-query tile, 128-key iters.
// wave w: strip = w>>1 (16 query rows), half = w&1 (which 64 keys of the tile).
__global__ __launch_bounds__(512) void attn_k(const unsigned short* __restrict__ Qb,
                                              const unsigned short* __restrict__ Kb,
                                              const unsigned short* __restrict__ Vt,
                                              const int* __restrict__ mask,
                                              float* __restrict__ out) {
    __shared__ __align__(16) char smem[18432 + 17408 + 17408 + 256];
    unsigned short* Ks = (unsigned short*)smem;                    // 128 x 72
    unsigned short* Vs = (unsigned short*)(smem + 18432);          // 64 x 136
    unsigned short* Ps = (unsigned short*)(smem + 18432 + 17408);  // 64 x 136
    float* dens = (float*)(smem + 18432 + 17408 + 17408);          // 64
    float* Os   = (float*)smem;                                    // 64 x 68 (reuse K)

    int tid  = threadIdx.x;
    int l    = tid & 63;
    int wv   = tid >> 6;
    int m    = l & 15;
    int quad = l >> 4;
    int strip = wv >> 1;
    int half  = wv & 1;
    int b  = blockIdx.x >> 6;
    int q0 = (blockIdx.x & 63) * 64;

    const int* maskb = mask + b * 4096;
    const unsigned short* Qg = Qb + (b * 4096 + q0) * 64;
    const unsigned short* Kg = Kb + b * 4096 * 64;
    const unsigned short* Vg = Vt + b * 64 * 4096;

    // Q strip resident in registers (A-frags for both k-steps)
    short8 qa[2];
#pragma unroll
    for (int ks = 0; ks < 2; ks++)
        qa[ks] = *(const short8*)(Qg + (strip * 16 + m) * 64 + ks * 32 + quad * 8);

    floatx4 ofrag[4];
#pragma unroll
    for (int i = 0; i < 4; i++) ofrag[i] = (floatx4)(0.f);
    if (tid < 64) dens[tid] = 0.f;

    for (int kt = 0; kt < 32; kt++) {
        int k0 = kt * 128;
        __syncthreads();   // prior iter's LDS reads done before overwrite
        // stage K tile 128x64 bf16
#pragma unroll
        for (int i = 0; i < 2; i++) {
            int idx = tid + i * 512;
            int row = idx >> 3, seg = idx & 7;
            *(int4*)(Ks + row * 72 + seg * 8) =
                *(const int4*)(Kg + (k0 + row) * 64 + seg * 8);
        }
        // stage V^T tile 64x128 bf16
#pragma unroll
        for (int i = 0; i < 2; i++) {
            int idx = tid + i * 512;
            int row = idx >> 4, seg = idx & 15;
            *(int4*)(Vs + row * 136 + seg * 8) =
                *(const int4*)(Vg + row * 4096 + k0 + seg * 8);
        }
        __syncthreads();

        // S = Q Ktile^T  (16 x 64 per wave)
        floatx4 sfr[4];
#pragma unroll
        for (int ct = 0; ct < 4; ct++) sfr[ct] = (floatx4)(0.f);
#pragma unroll
        for (int ks = 0; ks < 2; ks++) {
#pragma unroll
            for (int ct = 0; ct < 4; ct++) {
                short8 kb = *(const short8*)(Ks + (half * 64 + ct * 16 + m) * 72 + ks * 32 + quad * 8);
                sfr[ct] = __builtin_amdgcn_mfma_f32_16x16x32_bf16(qa[ks], kb, sfr[ct], 0, 0, 0);
            }
        }

        // exp (no max-subtraction: |logit| <= ~3, fp32-safe)
        floatx4 p[4];
#pragma unroll
        for (int ct = 0; ct < 4; ct++)
#pragma unroll
            for (int r = 0; r < 4; r++)
                p[ct][r] = exp2f(sfr[ct][r] * 0.18033688011112042f); // log2(e)/8

        // row denominators: sum over this wave's 64 keys, butterfly over 16 lanes
        floatx4 ts = p[0] + p[1] + p[2] + p[3];
#pragma unroll
        for (int off = 1; off < 16; off <<= 1)
#pragma unroll
            for (int r = 0; r < 4; r++)
                ts[r] += __shfl_xor(ts[r], off, 64);
        if (m == 0) {
#pragma unroll
            for (int r = 0; r < 4; r++)
                atomicAdd(&dens[strip * 16 + quad * 4 + r], ts[r]);
        }

        // mask (post-softmax -inf fill semantics) + store P as bf16 A-operand tile
#pragma unroll
        for (int ct = 0; ct < 4; ct++) {
            int key = k0 + half * 64 + ct * 16 + m;
            int mv = maskb[key];
#pragma unroll
            for (int r = 0; r < 4; r++) {
                float pv = mv ? p[ct][r] : -__builtin_inff();
                Ps[(strip * 16 + quad * 4 + r) * 136 + half * 64 + ct * 16 + m] = f2bf(pv);
            }
        }
        __syncthreads();   // P visible

        // O += P Vtile  (each wave: its 64-key half, all 64 d-cols)
#pragma unroll
        for (int ks = 0; ks < 2; ks++) {
            short8 pa = *(const short8*)(Ps + (strip * 16 + m) * 136 + half * 64 + ks * 32 + quad * 8);
#pragma unroll
            for (int dt = 0; dt < 4; dt++) {
                short8 vb = *(const short8*)(Vs + (dt * 16 + m) * 136 + half * 64 + ks * 32 + quad * 8);
                ofrag[dt] = __builtin_amdgcn_mfma_f32_16x16x32_bf16(pa, vb, ofrag[dt], 0, 0, 0);
            }
        }
    }

    // epilogue: cross-half reduce via LDS, divide by den, store fp32
    __syncthreads();
    if (half == 1) {
#pragma unroll
        for (int dt = 0; dt < 4; dt++)
#pragma unroll
            for (int r = 0; r < 4; r++)
                Os[(strip * 16 + quad * 4 + r) * 68 + dt * 16 + m] = ofrag[dt][r];
    }
    __syncthreads();
    if (half == 0) {
#pragma unroll
        for (int r = 0; r < 4; r++) {
            int row = strip * 16 + quad * 4 + r;
            float inv = 1.0f / dens[row];
#pragma unroll
            for (int dt = 0; dt < 4; dt++) {
                float v = ofrag[dt][r] + Os[row * 68 + dt * 16 + m];
                out[(b * 4096 + q0 + row) * 64 + dt * 16 + m] = v * inv;
            }
        }
    }
}

extern "C" void kernel_launch(void* const* d_in, const int* in_sizes, int n_in,
                              void* d_out, int out_size, void* d_ws, size_t ws_size,
                              hipStream_t stream) {
    const float* x  = (const float*)d_in[0];
    const int* mask = (const int*)d_in[1];
    const float* Wq = (const float*)d_in[2];
    const float* bq = (const float*)d_in[3];
    const float* Wk = (const float*)d_in[4];
    const float* bk = (const float*)d_in[5];
    const float* Wv = (const float*)d_in[6];
    const float* bv = (const float*)d_in[7];
    float* out = (float*)d_out;

    char* ws = (char*)d_ws;
    unsigned short* Wt = (unsigned short*)(ws);             // 192 KB: bf16 [3][64][512]
    unsigned short* Qb = (unsigned short*)(ws + 0x40000);   // 2 MB: bf16 [B*S][64]
    unsigned short* Kb = (unsigned short*)(ws + 0x240000);  // 2 MB
    unsigned short* Vt = (unsigned short*)(ws + 0x440000);  // 2 MB: bf16 [B][64][S]

    wtrans_k<<<384, 256, 0, stream>>>(Wq, Wk, Wv, Wt);
    proj_k<<<256, 256, 0, stream>>>(x, Wt, bq, bk, bv, Qb, Kb, Vt);
    attn_k<<<256, 512, 0, stream>>>(Qb, Kb, Vt, mask, out);
}